// Round 1
// baseline (151.923 us; speedup 1.0000x reference)
//
#include <hip/hip_runtime.h>

#define Hn 224
#define HWn (224*224)
#define B_ 16
#define CIN_ 64
#define COUT_ 64
#define TX 32
#define TY 32
#define OCB 8

// Kernel 1: S[b,y,x] = sum_ic x[b,ic,y,x]   (float4-vectorized)
__global__ __launch_bounds__(256) void chan_sum_kernel(const float* __restrict__ x,
                                                       float* __restrict__ S) {
    int idx = blockIdx.x * 256 + threadIdx.x;           // one float4 (4 pixels)
    const int npix4 = B_ * HWn / 4;                      // 200704
    if (idx >= npix4) return;
    const int s4 = HWn / 4;                              // 12544
    int b  = idx / s4;
    int p4 = idx - b * s4;
    const float4* xb = (const float4*)x + (size_t)b * CIN_ * s4 + p4;

    float4 a0 = xb[0 * s4];
    float4 a1 = xb[1 * s4];
    float4 a2 = xb[2 * s4];
    float4 a3 = xb[3 * s4];
    #pragma unroll 4
    for (int c = 4; c < CIN_; c += 4) {
        float4 v0 = xb[(c + 0) * s4];
        float4 v1 = xb[(c + 1) * s4];
        float4 v2 = xb[(c + 2) * s4];
        float4 v3 = xb[(c + 3) * s4];
        a0.x += v0.x; a0.y += v0.y; a0.z += v0.z; a0.w += v0.w;
        a1.x += v1.x; a1.y += v1.y; a1.z += v1.z; a1.w += v1.w;
        a2.x += v2.x; a2.y += v2.y; a2.z += v2.z; a2.w += v2.w;
        a3.x += v3.x; a3.y += v3.y; a3.z += v3.z; a3.w += v3.w;
    }
    float4 r;
    r.x = (a0.x + a1.x) + (a2.x + a3.x);
    r.y = (a0.y + a1.y) + (a2.y + a3.y);
    r.z = (a0.z + a1.z) + (a2.z + a3.z);
    r.w = (a0.w + a1.w) + (a2.w + a3.w);
    ((float4*)S)[idx] = r;
}

// Kernel 2: out[b,oc,y,x] = sum_{ky,kx} K[oc,0,ky,kx] * S[b,(y+4-ky)%224,(x+4-kx)%224]
// Block: one 32x32 output tile of one image, for 8 output channels.
__global__ __launch_bounds__(256) void conv_kernel(const float* __restrict__ S,
                                                   const float* __restrict__ K,
                                                   float* __restrict__ out) {
    __shared__ float sT[TY + 6][40];        // 38 rows x 38 cols used, stride 40
    __shared__ float sW[OCB * 49];

    const int tile = blockIdx.x;            // 0..48  (7x7 tiles)
    const int ocg  = blockIdx.y;            // 0..7
    const int b    = blockIdx.z;            // 0..15
    const int ty0 = (tile / 7) * TY;
    const int tx0 = (tile % 7) * TX;

    const float* Sb = S + (size_t)b * HWn;

    // stage halo tile (with circular wrap) into LDS
    for (int i = threadIdx.x; i < 38 * 38; i += 256) {
        int r = i / 38, c = i - r * 38;
        int gy = ty0 - 2 + r; gy = (gy + Hn) % Hn;
        int gx = tx0 - 2 + c; gx = (gx + Hn) % Hn;
        sT[r][c] = Sb[gy * Hn + gx];
    }
    // stage this group's weights (channel 0 only, per reference bug)
    for (int i = threadIdx.x; i < OCB * 49; i += 256) {
        int oc = ocg * OCB + i / 49;
        sW[i] = K[(size_t)oc * (CIN_ * 49) + (i - (i / 49) * 49)];
    }
    __syncthreads();

    const int tty = threadIdx.x >> 3;          // 0..31  output row in tile
    const int lx0 = (threadIdx.x & 7) * 4;     // 0,4,...,28 output col base

    float* outb = out + ((size_t)b * COUT_ + (size_t)ocg * OCB) * HWn
                      + (ty0 + tty) * Hn + tx0 + lx0;

    for (int oc = 0; oc < OCB; ++oc) {
        float w[49];
        #pragma unroll
        for (int i = 0; i < 49; ++i) w[i] = sW[oc * 49 + i];

        float4 acc = make_float4(0.f, 0.f, 0.f, 0.f);
        #pragma unroll
        for (int ky = 0; ky < 7; ++ky) {
            const float* row = &sT[tty + 6 - ky][lx0];
            float s[10];
            #pragma unroll
            for (int i = 0; i < 10; ++i) s[i] = row[i];
            #pragma unroll
            for (int kx = 0; kx < 7; ++kx) {
                const float wv = w[ky * 7 + kx];
                acc.x += wv * s[6 - kx + 0];
                acc.y += wv * s[6 - kx + 1];
                acc.z += wv * s[6 - kx + 2];
                acc.w += wv * s[6 - kx + 3];
            }
        }
        *(float4*)(outb + (size_t)oc * HWn) = acc;
    }
}

extern "C" void kernel_launch(void* const* d_in, const int* in_sizes, int n_in,
                              void* d_out, int out_size, void* d_ws, size_t ws_size,
                              hipStream_t stream) {
    const float* x = (const float*)d_in[0];   // [16,64,224,224] f32
    const float* K = (const float*)d_in[1];   // [64,64,7,7] f32
    float* out = (float*)d_out;               // [16,64,224,224] f32
    float* S = (float*)d_ws;                  // [16,224,224] f32 = 3.2 MB

    const int npix4 = B_ * HWn / 4;
    chan_sum_kernel<<<(npix4 + 255) / 256, 256, 0, stream>>>(x, S);

    dim3 g2(49, COUT_ / OCB, B_);
    conv_kernel<<<g2, 256, 0, stream>>>(S, K, out);
}

// Round 2
// 146.829 us; speedup vs baseline: 1.0347x; 1.0347x over previous
//
#include <hip/hip_runtime.h>

#define Hn 224
#define HWn (224*224)
#define B_ 16
#define CIN_ 64
#define COUT_ 64
#define TX 32
#define TY 32
#define OCB 8

// Kernel 1: S[b,y,x] = sum_ic x[b,ic,y,x]   (float4-vectorized)
__global__ __launch_bounds__(256) void chan_sum_kernel(const float* __restrict__ x,
                                                       float* __restrict__ S) {
    int idx = blockIdx.x * 256 + threadIdx.x;           // one float4 (4 pixels)
    const int npix4 = B_ * HWn / 4;                      // 200704
    if (idx >= npix4) return;
    const int s4 = HWn / 4;                              // 12544
    int b  = idx / s4;
    int p4 = idx - b * s4;
    const float4* xb = (const float4*)x + (size_t)b * CIN_ * s4 + p4;

    float4 a0 = xb[0 * s4];
    float4 a1 = xb[1 * s4];
    float4 a2 = xb[2 * s4];
    float4 a3 = xb[3 * s4];
    #pragma unroll 4
    for (int c = 4; c < CIN_; c += 4) {
        float4 v0 = xb[(c + 0) * s4];
        float4 v1 = xb[(c + 1) * s4];
        float4 v2 = xb[(c + 2) * s4];
        float4 v3 = xb[(c + 3) * s4];
        a0.x += v0.x; a0.y += v0.y; a0.z += v0.z; a0.w += v0.w;
        a1.x += v1.x; a1.y += v1.y; a1.z += v1.z; a1.w += v1.w;
        a2.x += v2.x; a2.y += v2.y; a2.z += v2.z; a2.w += v2.w;
        a3.x += v3.x; a3.y += v3.y; a3.z += v3.z; a3.w += v3.w;
    }
    float4 r;
    r.x = (a0.x + a1.x) + (a2.x + a3.x);
    r.y = (a0.y + a1.y) + (a2.y + a3.y);
    r.z = (a0.z + a1.z) + (a2.z + a3.z);
    r.w = (a0.w + a1.w) + (a2.w + a3.w);
    ((float4*)S)[idx] = r;
}

// Kernel 2: out[b,oc,y,x] = sum_{ky,kx} K[oc,0,ky,kx] * S[b,(y+4-ky)%224,(x+4-kx)%224]
// Block: one 32x32 output tile of one image, for 8 output channels.
// Rows hoisted to registers (oc-invariant); weights read as aligned b128.
__global__ __launch_bounds__(256) void conv_kernel(const float* __restrict__ S,
                                                   const float* __restrict__ K,
                                                   float* __restrict__ out) {
    __shared__ float sT[TY + 6][40];        // 38 rows x 38 cols used, stride 40
    __shared__ float sW[OCB * 52];          // stride 52 -> 16B-aligned per oc

    const int tile = blockIdx.x;            // 0..48  (7x7 tiles)
    const int ocg  = blockIdx.y;            // 0..7
    const int b    = blockIdx.z;            // 0..15
    const int ty0 = (tile / 7) * TY;
    const int tx0 = (tile % 7) * TX;

    const float* Sb = S + (size_t)b * HWn;

    // stage halo tile (with circular wrap) into LDS
    for (int i = threadIdx.x; i < 38 * 38; i += 256) {
        int r = i / 38, c = i - r * 38;
        int gy = ty0 - 2 + r; gy = (gy + Hn) % Hn;
        int gx = tx0 - 2 + c; gx = (gx + Hn) % Hn;
        sT[r][c] = Sb[gy * Hn + gx];
    }
    // stage this group's weights (in-channel 0 only, per reference bug)
    for (int i = threadIdx.x; i < OCB * 49; i += 256) {
        int ocl = i / 49, j = i - ocl * 49;
        sW[ocl * 52 + j] = K[(size_t)(ocg * OCB + ocl) * (CIN_ * 49) + j];
    }
    __syncthreads();

    const int tty = threadIdx.x >> 3;          // 0..31  output row in tile
    const int lx0 = (threadIdx.x & 7) * 4;     // 0,4,...,28 output col base

    // hoist the 7x10 input window into registers (oc-invariant)
    float s[70];
    #pragma unroll
    for (int r = 0; r < 7; ++r) {
        const float* base = &sT[tty + r][lx0];             // 16B-aligned
        *(float4*)&s[r * 10 + 0] = *(const float4*)&base[0];
        *(float4*)&s[r * 10 + 4] = *(const float4*)&base[4];
        *(float2*)&s[r * 10 + 8] = *(const float2*)&base[8];
    }

    float* outb = out + ((size_t)b * COUT_ + (size_t)ocg * OCB) * HWn
                      + (ty0 + tty) * Hn + tx0 + lx0;

    for (int oc = 0; oc < OCB; ++oc) {
        float w[52];
        #pragma unroll
        for (int i = 0; i < 13; ++i)
            *(float4*)&w[i * 4] = *(const float4*)&sW[oc * 52 + i * 4];

        float4 acc = make_float4(0.f, 0.f, 0.f, 0.f);
        #pragma unroll
        for (int ky = 0; ky < 7; ++ky) {
            #pragma unroll
            for (int kx = 0; kx < 7; ++kx) {
                const float wv = w[ky * 7 + kx];
                const int si = (6 - ky) * 10 + (6 - kx);   // compile-time
                acc.x += wv * s[si + 0];
                acc.y += wv * s[si + 1];
                acc.z += wv * s[si + 2];
                acc.w += wv * s[si + 3];
            }
        }
        *(float4*)(outb + (size_t)oc * HWn) = acc;
    }
}

extern "C" void kernel_launch(void* const* d_in, const int* in_sizes, int n_in,
                              void* d_out, int out_size, void* d_ws, size_t ws_size,
                              hipStream_t stream) {
    const float* x = (const float*)d_in[0];   // [16,64,224,224] f32
    const float* K = (const float*)d_in[1];   // [64,64,7,7] f32
    float* out = (float*)d_out;               // [16,64,224,224] f32
    float* S = (float*)d_ws;                  // [16,224,224] f32 = 3.2 MB

    const int npix4 = B_ * HWn / 4;
    chan_sum_kernel<<<(npix4 + 255) / 256, 256, 0, stream>>>(x, S);

    dim3 g2(49, COUT_ / OCB, B_);
    conv_kernel<<<g2, 256, 0, stream>>>(S, K, out);
}

// Round 3
// 139.770 us; speedup vs baseline: 1.0870x; 1.0505x over previous
//
#include <hip/hip_runtime.h>

#define Hn 224
#define HWn (224*224)
#define B_ 16
#define CIN_ 64
#define COUT_ 64
#define TX 32
#define TY 32
#define OCB 8

// Kernel 1: S[b,y,x] = sum_ic x[b,ic,y,x]   (float4-vectorized)
__global__ __launch_bounds__(256) void chan_sum_kernel(const float* __restrict__ x,
                                                       float* __restrict__ S) {
    int idx = blockIdx.x * 256 + threadIdx.x;           // one float4 (4 pixels)
    const int npix4 = B_ * HWn / 4;                      // 200704
    if (idx >= npix4) return;
    const int s4 = HWn / 4;                              // 12544
    int b  = idx / s4;
    int p4 = idx - b * s4;
    const float4* xb = (const float4*)x + (size_t)b * CIN_ * s4 + p4;

    float4 a0 = xb[0 * s4];
    float4 a1 = xb[1 * s4];
    float4 a2 = xb[2 * s4];
    float4 a3 = xb[3 * s4];
    #pragma unroll 4
    for (int c = 4; c < CIN_; c += 4) {
        float4 v0 = xb[(c + 0) * s4];
        float4 v1 = xb[(c + 1) * s4];
        float4 v2 = xb[(c + 2) * s4];
        float4 v3 = xb[(c + 3) * s4];
        a0.x += v0.x; a0.y += v0.y; a0.z += v0.z; a0.w += v0.w;
        a1.x += v1.x; a1.y += v1.y; a1.z += v1.z; a1.w += v1.w;
        a2.x += v2.x; a2.y += v2.y; a2.z += v2.z; a2.w += v2.w;
        a3.x += v3.x; a3.y += v3.y; a3.z += v3.z; a3.w += v3.w;
    }
    float4 r;
    r.x = (a0.x + a1.x) + (a2.x + a3.x);
    r.y = (a0.y + a1.y) + (a2.y + a3.y);
    r.z = (a0.z + a1.z) + (a2.z + a3.z);
    r.w = (a0.w + a1.w) + (a2.w + a3.w);
    ((float4*)S)[idx] = r;
}

// Kernel 2: out[b,oc,y,x] = sum_{ky,kx} K[oc,0,ky,kx] * S[b,(y+4-ky)%224,(x+4-kx)%224]
// Block: one 32x32 output tile of one image, for 8 output channels.
// Rows in registers (oc-invariant, from LDS); weights via block-uniform
// global loads -> SGPRs (s_load), zero LDS / zero VGPR cost.
__global__ __launch_bounds__(256) void conv_kernel(const float* __restrict__ S,
                                                   const float* __restrict__ K,
                                                   float* __restrict__ out) {
    __shared__ float sT[TY + 6][40];        // 38 rows x 38 cols used, stride 40

    const int tile = blockIdx.x;            // 0..48  (7x7 tiles)
    const int ocg  = blockIdx.y;            // 0..7
    const int b    = blockIdx.z;            // 0..15
    const int ty0 = (tile / 7) * TY;
    const int tx0 = (tile % 7) * TX;

    const float* Sb = S + (size_t)b * HWn;

    // stage halo tile (with circular wrap) into LDS; branchless wrap
    for (int i = threadIdx.x; i < 38 * 38; i += 256) {
        int r = i / 38, c = i - r * 38;
        int gy = ty0 - 2 + r; if (gy < 0) gy += Hn; if (gy >= Hn) gy -= Hn;
        int gx = tx0 - 2 + c; if (gx < 0) gx += Hn; if (gx >= Hn) gx -= Hn;
        sT[r][c] = Sb[gy * Hn + gx];
    }
    __syncthreads();

    const int tty = threadIdx.x >> 3;          // 0..31  output row in tile
    const int lx0 = (threadIdx.x & 7) * 4;     // 0,4,...,28 output col base

    // hoist the 7x10 input window into registers (oc-invariant)
    float s[70];
    #pragma unroll
    for (int r = 0; r < 7; ++r) {
        const float* base = &sT[tty + r][lx0];             // 16B-aligned
        *(float4*)&s[r * 10 + 0] = *(const float4*)&base[0];
        *(float4*)&s[r * 10 + 4] = *(const float4*)&base[4];
        *(float2*)&s[r * 10 + 8] = *(const float2*)&base[8];
    }

    float* outb = out + ((size_t)b * COUT_ + (size_t)ocg * OCB) * HWn
                      + (ty0 + tty) * Hn + tx0 + lx0;

    for (int oc = 0; oc < OCB; ++oc) {
        // block-uniform pointer + literal offsets -> scalar (SGPR) loads
        const float* __restrict__ wp = K + (size_t)(ocg * OCB + oc) * (CIN_ * 49);
        float w[49];
        #pragma unroll
        for (int i = 0; i < 49; ++i) w[i] = wp[i];

        float4 acc = make_float4(0.f, 0.f, 0.f, 0.f);
        #pragma unroll
        for (int ky = 0; ky < 7; ++ky) {
            #pragma unroll
            for (int kx = 0; kx < 7; ++kx) {
                const float wv = w[ky * 7 + kx];
                const int si = (6 - ky) * 10 + (6 - kx);   // compile-time
                acc.x += wv * s[si + 0];
                acc.y += wv * s[si + 1];
                acc.z += wv * s[si + 2];
                acc.w += wv * s[si + 3];
            }
        }
        *(float4*)(outb + (size_t)oc * HWn) = acc;
    }
}

extern "C" void kernel_launch(void* const* d_in, const int* in_sizes, int n_in,
                              void* d_out, int out_size, void* d_ws, size_t ws_size,
                              hipStream_t stream) {
    const float* x = (const float*)d_in[0];   // [16,64,224,224] f32
    const float* K = (const float*)d_in[1];   // [64,64,7,7] f32
    float* out = (float*)d_out;               // [16,64,224,224] f32
    float* S = (float*)d_ws;                  // [16,224,224] f32 = 3.2 MB

    const int npix4 = B_ * HWn / 4;
    chan_sum_kernel<<<(npix4 + 255) / 256, 256, 0, stream>>>(x, S);

    dim3 g2(49, COUT_ / OCB, B_);
    conv_kernel<<<g2, 256, 0, stream>>>(S, K, out);
}

// Round 4
// 121.873 us; speedup vs baseline: 1.2466x; 1.1468x over previous
//
#include <hip/hip_runtime.h>

#define Hn 224
#define HWn (224*224)
#define B_ 16
#define CIN_ 64
#define COUT_ 64
#define TX 32
#define TY 32
#define OCB 8

// Kernel 1: S[b,y,x] = sum_ic x[b,ic,y,x]   (float4-vectorized)
__global__ __launch_bounds__(256) void chan_sum_kernel(const float* __restrict__ x,
                                                       float* __restrict__ S) {
    int idx = blockIdx.x * 256 + threadIdx.x;           // one float4 (4 pixels)
    const int npix4 = B_ * HWn / 4;                      // 200704
    if (idx >= npix4) return;
    const int s4 = HWn / 4;                              // 12544
    int b  = idx / s4;
    int p4 = idx - b * s4;
    const float4* xb = (const float4*)x + (size_t)b * CIN_ * s4 + p4;

    float4 a0 = xb[0 * s4];
    float4 a1 = xb[1 * s4];
    float4 a2 = xb[2 * s4];
    float4 a3 = xb[3 * s4];
    #pragma unroll 4
    for (int c = 4; c < CIN_; c += 4) {
        float4 v0 = xb[(c + 0) * s4];
        float4 v1 = xb[(c + 1) * s4];
        float4 v2 = xb[(c + 2) * s4];
        float4 v3 = xb[(c + 3) * s4];
        a0.x += v0.x; a0.y += v0.y; a0.z += v0.z; a0.w += v0.w;
        a1.x += v1.x; a1.y += v1.y; a1.z += v1.z; a1.w += v1.w;
        a2.x += v2.x; a2.y += v2.y; a2.z += v2.z; a2.w += v2.w;
        a3.x += v3.x; a3.y += v3.y; a3.z += v3.z; a3.w += v3.w;
    }
    float4 r;
    r.x = (a0.x + a1.x) + (a2.x + a3.x);
    r.y = (a0.y + a1.y) + (a2.y + a3.y);
    r.z = (a0.z + a1.z) + (a2.z + a3.z);
    r.w = (a0.w + a1.w) + (a2.w + a3.w);
    ((float4*)S)[idx] = r;
}

// Kernel 2: out[b,oc,y,x] = sum_{ky,kx} K[oc,0,ky,kx] * S[b,(y+4-ky)%224,(x+4-kx)%224]
// ky-outer / oc-inner: acc[8] float4 (32 VGPR), rolling s[10] row (10 VGPR),
// weights as uniform s_loads. __launch_bounds__(256,4) -> VGPR<=128, 4 waves/SIMD.
__global__ __launch_bounds__(256, 4) void conv_kernel(const float* __restrict__ S,
                                                      const float* __restrict__ K,
                                                      float* __restrict__ out) {
    __shared__ float sT[TY + 6][40];        // 38 rows x 38 cols used, stride 40

    const int tile = blockIdx.x;            // 0..48  (7x7 tiles)
    const int ocg  = blockIdx.y;            // 0..7
    const int b    = blockIdx.z;            // 0..15
    const int ty0 = (tile / 7) * TY;
    const int tx0 = (tile % 7) * TX;

    const float* Sb = S + (size_t)b * HWn;

    // stage halo tile (with circular wrap) into LDS; branchless wrap
    for (int i = threadIdx.x; i < 38 * 38; i += 256) {
        int r = i / 38, c = i - r * 38;
        int gy = ty0 - 2 + r; if (gy < 0) gy += Hn; if (gy >= Hn) gy -= Hn;
        int gx = tx0 - 2 + c; if (gx < 0) gx += Hn; if (gx >= Hn) gx -= Hn;
        sT[r][c] = Sb[gy * Hn + gx];
    }
    __syncthreads();

    const int tty = threadIdx.x >> 3;          // 0..31  output row in tile
    const int lx0 = (threadIdx.x & 7) * 4;     // 0,4,...,28 output col base

    const float* __restrict__ Kg = K + (size_t)(ocg * OCB) * (CIN_ * 49);

    float4 acc[OCB];
    #pragma unroll
    for (int i = 0; i < OCB; ++i) acc[i] = make_float4(0.f, 0.f, 0.f, 0.f);

    #pragma unroll
    for (int ky = 0; ky < 7; ++ky) {
        const float* base = &sT[tty + 6 - ky][lx0];       // 16B-aligned
        float s[10];
        *(float4*)&s[0] = *(const float4*)&base[0];
        *(float4*)&s[4] = *(const float4*)&base[4];
        *(float2*)&s[8] = *(const float2*)&base[8];

        #pragma unroll
        for (int oc = 0; oc < OCB; ++oc) {
            // block-uniform address + literal offsets -> scalar loads
            const float* __restrict__ wp = Kg + oc * (CIN_ * 49) + ky * 7;
            #pragma unroll
            for (int kx = 0; kx < 7; ++kx) {
                const float wv = wp[kx];
                const int si = 6 - kx;                    // compile-time
                acc[oc].x += wv * s[si + 0];
                acc[oc].y += wv * s[si + 1];
                acc[oc].z += wv * s[si + 2];
                acc[oc].w += wv * s[si + 3];
            }
        }
    }

    float* outb = out + ((size_t)b * COUT_ + (size_t)ocg * OCB) * HWn
                      + (ty0 + tty) * Hn + tx0 + lx0;
    #pragma unroll
    for (int oc = 0; oc < OCB; ++oc)
        *(float4*)(outb + (size_t)oc * HWn) = acc[oc];
}

extern "C" void kernel_launch(void* const* d_in, const int* in_sizes, int n_in,
                              void* d_out, int out_size, void* d_ws, size_t ws_size,
                              hipStream_t stream) {
    const float* x = (const float*)d_in[0];   // [16,64,224,224] f32
    const float* K = (const float*)d_in[1];   // [64,64,7,7] f32
    float* out = (float*)d_out;               // [16,64,224,224] f32
    float* S = (float*)d_ws;                  // [16,224,224] f32 = 3.2 MB

    const int npix4 = B_ * HWn / 4;
    chan_sum_kernel<<<(npix4 + 255) / 256, 256, 0, stream>>>(x, S);

    dim3 g2(49, COUT_ / OCB, B_);
    conv_kernel<<<g2, 256, 0, stream>>>(S, K, out);
}